// Round 5
// baseline (278.902 us; speedup 1.0000x reference)
//
#include <hip/hip_runtime.h>

#define N_NODES 50000
#define N_EDGES 600000
#define N_GRAPHS 512

typedef unsigned int u32;
typedef unsigned short u16;
typedef __attribute__((ext_vector_type(8))) short bf16x8;
typedef __attribute__((ext_vector_type(4))) float f32x4;

__device__ __forceinline__ float bflo(u32 v) { return __uint_as_float(v << 16); }
__device__ __forceinline__ float bfhi(u32 v) { return __uint_as_float(v & 0xffff0000u); }
__device__ __forceinline__ u16 f2bf(float f) {
    u32 x = __float_as_uint(f);
    return (u16)((x + 0x7fffu + ((x >> 16) & 1u)) >> 16);
}
__device__ __forceinline__ void addrow(float* a, uint4 v) {
    a[0] += bflo(v.x); a[1] += bfhi(v.x);
    a[2] += bflo(v.y); a[3] += bfhi(v.y);
    a[4] += bflo(v.z); a[5] += bfhi(v.z);
    a[6] += bflo(v.w); a[7] += bfhi(v.w);
}

// ---------------- index-width detect (int32 vs int64 input layout) ----------
__global__ void detect_kernel(const int* __restrict__ ei, int* __restrict__ flag) {
    int lane = threadIdx.x;                 // 64 lanes
    int v = ei[2 * lane + 1];               // odd words: int64 high-words OR int32 src[2k+1]
    unsigned long long nz = __ballot(v != 0);
    if (lane == 0) *flag = (nz == 0ull) ? 1 : 0;   // all zero -> int64
}

__device__ __forceinline__ int idx_at(const int* __restrict__ a, int i, int wide) {
    return wide ? a[2 * i] : a[i];          // little-endian low word; values < 2^31
}

// ---------------- CSR build ----------------
__global__ void hist_kernel(const int* __restrict__ ei, const int* __restrict__ flag,
                            int* __restrict__ cnt) {
    int e = blockIdx.x * 256 + threadIdx.x;
    if (e >= N_EDGES) return;
    int w = *flag;
    const int* dst = ei + (w ? 2 * N_EDGES : N_EDGES);
    atomicAdd(&cnt[idx_at(dst, e, w)], 1);
}

__global__ void scan1(const int* __restrict__ cnt, int* __restrict__ excl,
                      int* __restrict__ bsum) {
    __shared__ int s[256];
    int tid = threadIdx.x;
    int i = blockIdx.x * 256 + tid;
    int v = (i < N_NODES) ? cnt[i] : 0;
    s[tid] = v; __syncthreads();
    for (int off = 1; off < 256; off <<= 1) {
        int t = (tid >= off) ? s[tid - off] : 0;
        __syncthreads();
        s[tid] += t;
        __syncthreads();
    }
    if (i < N_NODES) excl[i] = s[tid] - v;
    if (tid == 255) bsum[blockIdx.x] = s[255];
}

__global__ void scan2(int* __restrict__ bsum, int nb) {
    __shared__ int s[256];
    int tid = threadIdx.x;
    int v = (tid < nb) ? bsum[tid] : 0;
    s[tid] = v; __syncthreads();
    for (int off = 1; off < 256; off <<= 1) {
        int t = (tid >= off) ? s[tid - off] : 0;
        __syncthreads();
        s[tid] += t;
        __syncthreads();
    }
    if (tid < nb) bsum[tid] = s[tid] - v;
}

__global__ void scan3(int* __restrict__ offsets, const int* __restrict__ bsum,
                      int* __restrict__ cursor) {
    int i = blockIdx.x * 256 + threadIdx.x;
    if (i < N_NODES) {
        int off = offsets[i] + bsum[i >> 8];
        offsets[i] = off;
        cursor[i] = off;
    }
    if (i == 0) offsets[N_NODES] = N_EDGES;
}

__global__ void scatter_kernel(const int* __restrict__ ei, const int* __restrict__ flag,
                               int* __restrict__ cursor, int* __restrict__ ssrc) {
    int e = blockIdx.x * 256 + threadIdx.x;
    if (e >= N_EDGES) return;
    int w = *flag;
    const int* src = ei;
    const int* dst = ei + (w ? 2 * N_EDGES : N_EDGES);
    int d = idx_at(dst, e, w);
    int pos = atomicAdd(&cursor[d], 1);
    ssrc[pos] = idx_at(src, e, w);
}

// ---------------- converts ----------------
__global__ void cvt_x(const float* __restrict__ in, u16* __restrict__ out) {
    size_t i = (size_t)blockIdx.x * 256 + threadIdx.x;   // 1.6M threads, 4 elems each
    float4 v = *(const float4*)&in[i * 4];
    u32 o0 = (u32)f2bf(v.x) | ((u32)f2bf(v.y) << 16);
    u32 o1 = (u32)f2bf(v.z) | ((u32)f2bf(v.w) << 16);
    uint2 o; o.x = o0; o.y = o1;
    *(uint2*)&out[i * 4] = o;
}

// all 6 weight transposes in one launch: w [K][N] f32 -> wt [N][K] bf16
struct CvtDesc { const float* w; u16* wt; int K, N, bx, bstart; };
struct CvtAll { CvtDesc d[6]; };
__global__ void cvt_wt_all(CvtAll all) {
    __shared__ float tile[32][33];
    int b = blockIdx.x;
    int di = 0;
#pragma unroll
    for (int i = 1; i < 6; ++i) if (b >= all.d[i].bstart) di = i;
    CvtDesc d = all.d[di];
    int rel = b - d.bstart;
    int bk = (rel % d.bx) * 32, bn = (rel / d.bx) * 32;
    int tx = threadIdx.x & 31, ty = threadIdx.x >> 5;   // 32 x 8
#pragma unroll
    for (int yy = 0; yy < 32; yy += 8)
        tile[ty + yy][tx] = d.w[(size_t)(bk + ty + yy) * d.N + bn + tx];
    __syncthreads();
#pragma unroll
    for (int yy = 0; yy < 32; yy += 8)
        d.wt[(size_t)(bn + ty + yy) * d.K + bk + tx] = f2bf(tile[tx][ty + yy]);
}

// ---------------- fused GIN layer: agg -> GEMM1(+b,ReLU) -> GEMM2(+b,[ReLU]) ----
// xb: bf16 [N_NODES][128]; w1t: bf16 [DOUT][128]; w2t: bf16 [DOUT][DOUT]
// POOL: atomically add y rows into yout[f32 N_GRAPHS][DOUT] (pre-zeroed)
template <int DOUT, int RELU_OUT, int POOL>
__global__ __launch_bounds__(512) void fused_layer(
    const u16* __restrict__ xb, const int* __restrict__ offsets,
    const int* __restrict__ ssrc,
    const u16* __restrict__ w1t, const float* __restrict__ b1,
    const u16* __restrict__ w2t, const float* __restrict__ b2,
    const int* __restrict__ batch, const int* __restrict__ flagp,
    void* __restrict__ yout)
{
    __shared__ u16 hs[64 * 128];     // h tile, XOR-swizzled rows
    __shared__ u16 ts[64 * DOUT];    // relu(h@w1+b1) tile, XOR-swizzled
    const int tid = threadIdx.x;
    const int wave = tid >> 6, lane = tid & 63;
    const int g = lane >> 4;         // 4 groups of 16 lanes
    const int l = lane & 15;
    const int base = blockIdx.x * 64;
    const int wflag = POOL ? *flagp : 0;

    // ---- phase A: gather-aggregate; 4 neighbor rows in flight per wave ----
    // All __shfl ops run with the FULL wave active (uniform trip count);
    // only the loads/adds are predicated (divergent loads are defined,
    // divergent shfl is not).
    for (int i = 0; i < 8; ++i) {
        int rr = wave * 8 + i;
        int node = base + rr;
        if (node >= N_NODES) break;              // wave-uniform
        float acc[8] = {0.f, 0.f, 0.f, 0.f, 0.f, 0.f, 0.f, 0.f};
        int b0 = offsets[node];
        int deg = offsets[node + 1] - b0;        // wave-uniform
        int nid = (lane < deg) ? ssrc[b0 + lane] : 0;
        int dmain = deg > 64 ? 64 : deg;         // wave-uniform
        if (g == 0) {                            // self term, group 0 only
            uint4 sv = *(const uint4*)(xb + ((size_t)node << 7) + l * 8);
            addrow(acc, sv);
        }
        int nsteps = (dmain + 7) >> 3;           // wave-uniform
        int jj = g;                              // group g covers {g+4k}
        for (int k = 0; k < nsteps; ++k, jj += 8) {
            int s0 = __shfl(nid, jj);            // jj <= 59 always
            int s1 = __shfl(nid, jj + 4);        // jj+4 <= 63 always
            if (jj < dmain) {
                uint4 v0 = *(const uint4*)(xb + ((size_t)s0 << 7) + l * 8);
                addrow(acc, v0);
            }
            if (jj + 4 < dmain) {
                uint4 v1 = *(const uint4*)(xb + ((size_t)s1 << 7) + l * 8);
                addrow(acc, v1);
            }
        }
        for (int t = b0 + 64 + g; t < b0 + deg; t += 4) {   // rare deg>64 tail
            int s0 = ssrc[t];
            uint4 v0 = *(const uint4*)(xb + ((size_t)s0 << 7) + l * 8);
            addrow(acc, v0);
        }
        // reduce the 4 group partials (lanes l, l+16, l+32, l+48)
#pragma unroll
        for (int c = 0; c < 8; ++c) {
            acc[c] += __shfl_xor(acc[c], 16);
            acc[c] += __shfl_xor(acc[c], 32);
        }
        if (g == 0) {                            // ch c -> u16 index c ^ sw
            uint4 o;
            o.x = (u32)f2bf(acc[0]) | ((u32)f2bf(acc[1]) << 16);
            o.y = (u32)f2bf(acc[2]) | ((u32)f2bf(acc[3]) << 16);
            o.z = (u32)f2bf(acc[4]) | ((u32)f2bf(acc[5]) << 16);
            o.w = (u32)f2bf(acc[6]) | ((u32)f2bf(acc[7]) << 16);
            int c = (l * 8) ^ ((rr & 7) << 3);
            *(uint4*)&hs[rr * 128 + c] = o;
        }
    }
    __syncthreads();

    const int m = lane & 15;
    const int ko = (lane >> 4) * 8;
    const int rb = (wave & 3) * 16;               // row block (16 rows)
    const int cbase = (wave >> 2) * (DOUT / 2);   // col half
    constexpr int NT = DOUT / 32;                 // 16-col tiles per wave

    // ---- GEMM1: ts = relu(hs @ w1 + b1) ----
    {
        const int rr = rb + m;
        const int sw = (rr & 7) << 3;
        bf16x8 a1[4];
#pragma unroll
        for (int s = 0; s < 4; ++s)
            a1[s] = *(const bf16x8*)&hs[rr * 128 + ((s * 32 + ko) ^ sw)];
        f32x4 acc[NT];
#pragma unroll
        for (int nt = 0; nt < NT; ++nt) acc[nt] = (f32x4){0.f, 0.f, 0.f, 0.f};
#pragma unroll
        for (int nt = 0; nt < NT; ++nt) {
            int n = cbase + nt * 16 + m;
#pragma unroll
            for (int s = 0; s < 4; ++s) {
                bf16x8 bf = *(const bf16x8*)&w1t[(size_t)n * 128 + s * 32 + ko];
                acc[nt] = __builtin_amdgcn_mfma_f32_16x16x32_bf16(a1[s], bf, acc[nt], 0, 0, 0);
            }
        }
#pragma unroll
        for (int nt = 0; nt < NT; ++nt) {
            int n = cbase + nt * 16 + m;
            float bias = b1[n];
#pragma unroll
            for (int j2 = 0; j2 < 4; ++j2) {
                int dr = rb + (lane >> 4) * 4 + j2;   // D: col=lane&15, row=(lane>>4)*4+reg
                float v = fmaxf(acc[nt][j2] + bias, 0.f);
                ts[dr * DOUT + (n ^ ((dr & 7) << 3))] = f2bf(v);
            }
        }
    }
    __syncthreads();

    // ---- GEMM2: y = ts @ w2 + b2 ----
    {
        const int rr = rb + m;
        const int sw = (rr & 7) << 3;
        constexpr int KS = DOUT / 32;
        bf16x8 a2[KS];
#pragma unroll
        for (int s = 0; s < KS; ++s)
            a2[s] = *(const bf16x8*)&ts[rr * DOUT + ((s * 32 + ko) ^ sw)];
        f32x4 acc[NT];
#pragma unroll
        for (int nt = 0; nt < NT; ++nt) acc[nt] = (f32x4){0.f, 0.f, 0.f, 0.f};
#pragma unroll
        for (int nt = 0; nt < NT; ++nt) {
            int n = cbase + nt * 16 + m;
#pragma unroll
            for (int s = 0; s < KS; ++s) {
                bf16x8 bf = *(const bf16x8*)&w2t[(size_t)n * DOUT + s * 32 + ko];
                acc[nt] = __builtin_amdgcn_mfma_f32_16x16x32_bf16(a2[s], bf, acc[nt], 0, 0, 0);
            }
        }
        if (POOL) {
#pragma unroll
            for (int j2 = 0; j2 < 4; ++j2) {
                int dr = rb + (lane >> 4) * 4 + j2;
                int node = base + dr;
                if (node < N_NODES) {
                    int gid = idx_at(batch, node, wflag);
#pragma unroll
                    for (int nt = 0; nt < NT; ++nt) {
                        int n = cbase + nt * 16 + m;
                        float v = acc[nt][j2] + b2[n];
                        atomicAdd(&((float*)yout)[(size_t)gid * DOUT + n], v);
                    }
                }
            }
        } else {
#pragma unroll
            for (int nt = 0; nt < NT; ++nt) {
                int n = cbase + nt * 16 + m;
                float bias = b2[n];
#pragma unroll
                for (int j2 = 0; j2 < 4; ++j2) {
                    int dr = rb + (lane >> 4) * 4 + j2;
                    int node = base + dr;
                    if (node < N_NODES) {
                        float v = acc[nt][j2] + bias;
                        if (RELU_OUT) v = fmaxf(v, 0.f);
                        ((u16*)yout)[(size_t)node * DOUT + n] = f2bf(v);
                    }
                }
            }
        }
    }
}

extern "C" void kernel_launch(void* const* d_in, const int* in_sizes, int n_in,
                              void* d_out, int out_size, void* d_ws, size_t ws_size,
                              hipStream_t stream) {
    const float* x     = (const float*)d_in[0];
    const int*   ei    = (const int*)d_in[1];
    const int*   batch = (const int*)d_in[2];
    const float* w1[3] = {(const float*)d_in[3], (const float*)d_in[7],  (const float*)d_in[11]};
    const float* b1[3] = {(const float*)d_in[4], (const float*)d_in[8],  (const float*)d_in[12]};
    const float* w2[3] = {(const float*)d_in[5], (const float*)d_in[9],  (const float*)d_in[13]};
    const float* b2[3] = {(const float*)d_in[6], (const float*)d_in[10], (const float*)d_in[14]};
    float* out = (float*)d_out;

    char* ws = (char*)d_ws;
    int*   cursor  = (int*)(ws + 0);          // 50000 ints (also histogram counts)
    int*   offsets = (int*)(ws + 200192);     // 50001 ints
    int*   bsum    = (int*)(ws + 400640);     // 196 ints
    int*   flag    = (int*)(ws + 401664);     // 1 int
    int*   ssrc    = (int*)(ws + 401920);     // 600000 ints
    u16*   xb      = (u16*)(ws + 2801920);    // 50000*128 bf16
    u16*   yA      = (u16*)(ws + 15601920);   // 50000*128 bf16
    u16*   yB      = (u16*)(ws + 28401920);   // 50000*128 bf16
    u16*   wts     = (u16*)(ws + 41201920);   // transposed bf16 weights
    u16* w1t0 = wts +      0;   // [128][128]
    u16* w2t0 = wts +  16384;   // [128][128]
    u16* w1t1 = wts +  32768;   // [128][128]
    u16* w2t1 = wts +  49152;   // [128][128]
    u16* w1t2 = wts +  65536;   // [64][128]
    u16* w2t2 = wts +  73728;   // [64][64]

    detect_kernel<<<1, 64, 0, stream>>>(ei, flag);

    (void)hipMemsetAsync(cursor, 0, N_NODES * sizeof(int), stream);
    hist_kernel<<<(N_EDGES + 255) / 256, 256, 0, stream>>>(ei, flag, cursor);
    scan1<<<196, 256, 0, stream>>>(cursor, offsets, bsum);
    scan2<<<1, 256, 0, stream>>>(bsum, 196);
    scan3<<<196, 256, 0, stream>>>(offsets, bsum, cursor);
    scatter_kernel<<<(N_EDGES + 255) / 256, 256, 0, stream>>>(ei, flag, cursor, ssrc);

    cvt_x<<<6250, 256, 0, stream>>>(x, xb);
    CvtAll ca;
    ca.d[0] = {w1[0], w1t0, 128, 128, 4,  0};
    ca.d[1] = {w2[0], w2t0, 128, 128, 4, 16};
    ca.d[2] = {w1[1], w1t1, 128, 128, 4, 32};
    ca.d[3] = {w2[1], w2t1, 128, 128, 4, 48};
    ca.d[4] = {w1[2], w1t2, 128,  64, 4, 64};
    ca.d[5] = {w2[2], w2t2,  64,  64, 2, 72};
    cvt_wt_all<<<76, 256, 0, stream>>>(ca);

    (void)hipMemsetAsync(out, 0, (size_t)out_size * sizeof(float), stream);

    const int NB = (N_NODES + 63) / 64;   // 782
    fused_layer<128, 1, 0><<<NB, 512, 0, stream>>>(xb, offsets, ssrc, w1t0, b1[0], w2t0, b2[0], batch, flag, yA);
    fused_layer<128, 1, 0><<<NB, 512, 0, stream>>>(yA, offsets, ssrc, w1t1, b1[1], w2t1, b2[1], batch, flag, yB);
    fused_layer< 64, 0, 1><<<NB, 512, 0, stream>>>(yB, offsets, ssrc, w1t2, b1[2], w2t2, b2[2], batch, flag, out);
}

// Round 6
// 234.937 us; speedup vs baseline: 1.1871x; 1.1871x over previous
//
#include <hip/hip_runtime.h>

#define N_NODES 50000
#define N_EDGES 600000
#define N_GRAPHS 512

typedef unsigned int u32;
typedef unsigned short u16;
typedef __attribute__((ext_vector_type(8))) short bf16x8;
typedef __attribute__((ext_vector_type(4))) float f32x4;

__device__ __forceinline__ float bflo(u32 v) { return __uint_as_float(v << 16); }
__device__ __forceinline__ float bfhi(u32 v) { return __uint_as_float(v & 0xffff0000u); }
__device__ __forceinline__ u16 f2bf(float f) {
    u32 x = __float_as_uint(f);
    return (u16)((x + 0x7fffu + ((x >> 16) & 1u)) >> 16);
}

// ---------------- index-width detect (int32 vs int64 input layout) ----------
__global__ void detect_kernel(const int* __restrict__ ei, int* __restrict__ flag) {
    int lane = threadIdx.x;                 // 64 lanes
    int v = ei[2 * lane + 1];               // odd words: int64 high-words OR int32 src[2k+1]
    unsigned long long nz = __ballot(v != 0);
    if (lane == 0) *flag = (nz == 0ull) ? 1 : 0;   // all zero -> int64
}

__device__ __forceinline__ int idx_at(const int* __restrict__ a, int i, int wide) {
    return wide ? a[2 * i] : a[i];          // little-endian low word; values < 2^31
}

// ---------------- CSR build ----------------
__global__ void hist_kernel(const int* __restrict__ ei, const int* __restrict__ flag,
                            int* __restrict__ cnt) {
    int e = blockIdx.x * 256 + threadIdx.x;
    if (e >= N_EDGES) return;
    int w = *flag;
    const int* dst = ei + (w ? 2 * N_EDGES : N_EDGES);
    atomicAdd(&cnt[idx_at(dst, e, w)], 1);
}

__global__ void scan1(const int* __restrict__ cnt, int* __restrict__ excl,
                      int* __restrict__ bsum) {
    __shared__ int s[256];
    int tid = threadIdx.x;
    int i = blockIdx.x * 256 + tid;
    int v = (i < N_NODES) ? cnt[i] : 0;
    s[tid] = v; __syncthreads();
    for (int off = 1; off < 256; off <<= 1) {
        int t = (tid >= off) ? s[tid - off] : 0;
        __syncthreads();
        s[tid] += t;
        __syncthreads();
    }
    if (i < N_NODES) excl[i] = s[tid] - v;
    if (tid == 255) bsum[blockIdx.x] = s[255];
}

__global__ void scan2(int* __restrict__ bsum, int nb) {
    __shared__ int s[256];
    int tid = threadIdx.x;
    int v = (tid < nb) ? bsum[tid] : 0;
    s[tid] = v; __syncthreads();
    for (int off = 1; off < 256; off <<= 1) {
        int t = (tid >= off) ? s[tid - off] : 0;
        __syncthreads();
        s[tid] += t;
        __syncthreads();
    }
    if (tid < nb) bsum[tid] = s[tid] - v;
}

__global__ void scan3(int* __restrict__ offsets, const int* __restrict__ bsum,
                      int* __restrict__ cursor) {
    int i = blockIdx.x * 256 + threadIdx.x;
    if (i < N_NODES) {
        int off = offsets[i] + bsum[i >> 8];
        offsets[i] = off;
        cursor[i] = off;
    }
    if (i == 0) offsets[N_NODES] = N_EDGES;
}

__global__ void scatter_kernel(const int* __restrict__ ei, const int* __restrict__ flag,
                               int* __restrict__ cursor, int* __restrict__ ssrc) {
    int e = blockIdx.x * 256 + threadIdx.x;
    if (e >= N_EDGES) return;
    int w = *flag;
    const int* src = ei;
    const int* dst = ei + (w ? 2 * N_EDGES : N_EDGES);
    int d = idx_at(dst, e, w);
    int pos = atomicAdd(&cursor[d], 1);
    ssrc[pos] = idx_at(src, e, w);
}

// ---------------- converts ----------------
__global__ void cvt_x(const float* __restrict__ in, u16* __restrict__ out) {
    size_t i = (size_t)blockIdx.x * 256 + threadIdx.x;   // 1.6M threads, 4 elems each
    float4 v = *(const float4*)&in[i * 4];
    u32 o0 = (u32)f2bf(v.x) | ((u32)f2bf(v.y) << 16);
    u32 o1 = (u32)f2bf(v.z) | ((u32)f2bf(v.w) << 16);
    uint2 o; o.x = o0; o.y = o1;
    *(uint2*)&out[i * 4] = o;
}

// all 6 weight transposes in one launch: w [K][N] f32 -> wt [N][K] bf16
struct CvtDesc { const float* w; u16* wt; int K, N, bx, bstart; };
struct CvtAll { CvtDesc d[6]; };
__global__ void cvt_wt_all(CvtAll all) {
    __shared__ float tile[32][33];
    int b = blockIdx.x;
    int di = 0;
#pragma unroll
    for (int i = 1; i < 6; ++i) if (b >= all.d[i].bstart) di = i;
    CvtDesc d = all.d[di];
    int rel = b - d.bstart;
    int bk = (rel % d.bx) * 32, bn = (rel / d.bx) * 32;
    int tx = threadIdx.x & 31, ty = threadIdx.x >> 5;   // 32 x 8
#pragma unroll
    for (int yy = 0; yy < 32; yy += 8)
        tile[ty + yy][tx] = d.w[(size_t)(bk + ty + yy) * d.N + bn + tx];
    __syncthreads();
#pragma unroll
    for (int yy = 0; yy < 32; yy += 8)
        d.wt[(size_t)(bn + ty + yy) * d.K + bk + tx] = f2bf(tile[tx][ty + yy]);
}

// ---------------- fused GIN layer: agg -> GEMM1(+b,ReLU) -> GEMM2(+b,[ReLU]) ----
// xb: bf16 [N_NODES][128]; w1t: bf16 [DOUT][128]; w2t: bf16 [DOUT][DOUT]
// POOL: segment-reduce y rows in-block (batch sorted), few atomics into yout f32
template <int DOUT, int RELU_OUT, int POOL>
__global__ __launch_bounds__(512) void fused_layer(
    const u16* __restrict__ xb, const int* __restrict__ offsets,
    const int* __restrict__ ssrc,
    const u16* __restrict__ w1t, const float* __restrict__ b1,
    const u16* __restrict__ w2t, const float* __restrict__ b2,
    const int* __restrict__ batch, const int* __restrict__ flagp,
    void* __restrict__ yout)
{
    constexpr int YB_ST = 66;                          // f32 stride (bank-spread)
    constexpr int HSB = 64 * 128 * 2;                  // 16384 B
    constexpr int AB = POOL ? (64 * YB_ST * 4) : HSB;  // ybuf overlays dead hs
    constexpr int ABM = AB > HSB ? AB : HSB;
    __shared__ __attribute__((aligned(16))) char smemA[ABM];
    __shared__ __attribute__((aligned(16))) u16 ts[64 * DOUT];
    __shared__ int gids[64];
    u16* hs = (u16*)smemA;          // h tile, XOR-swizzled rows
    float* yb = (float*)smemA;      // POOL: f32 y stage (valid after hs is dead)

    const int tid = threadIdx.x;
    const int wave = tid >> 6, lane = tid & 63;
    const int base = blockIdx.x * 64;
    const int wflag = POOL ? *flagp : 0;

    if (POOL && tid < 64) {
        int node = base + tid;
        gids[tid] = (node < N_NODES) ? idx_at(batch, node, wflag) : -1;
    }

    // ---- phase A: gather-aggregate (whole-wave rows, 4-deep unroll) ----
    for (int i = 0; i < 8; ++i) {
        int rr = wave * 8 + i;
        int node = base + rr;
        if (node >= N_NODES) break;              // wave-uniform
        u32 self = *(const u32*)(xb + ((size_t)node << 7) + 2 * lane);
        float ax0 = bflo(self), ay0 = bfhi(self);
        float ax1 = 0.f, ay1 = 0.f, ax2 = 0.f, ay2 = 0.f, ax3 = 0.f, ay3 = 0.f;
        int b0 = offsets[node];
        int deg = offsets[node + 1] - b0;        // wave-uniform
        int nid = (lane < deg) ? ssrc[b0 + lane] : 0;
        int dmain = deg > 64 ? 64 : deg;
        int j = 0;
        for (; j + 4 <= dmain; j += 4) {         // 4 independent row loads
            int s0 = __shfl(nid, j);
            int s1 = __shfl(nid, j + 1);
            int s2 = __shfl(nid, j + 2);
            int s3 = __shfl(nid, j + 3);
            u32 v0 = *(const u32*)(xb + ((size_t)s0 << 7) + 2 * lane);
            u32 v1 = *(const u32*)(xb + ((size_t)s1 << 7) + 2 * lane);
            u32 v2 = *(const u32*)(xb + ((size_t)s2 << 7) + 2 * lane);
            u32 v3 = *(const u32*)(xb + ((size_t)s3 << 7) + 2 * lane);
            ax0 += bflo(v0); ay0 += bfhi(v0);
            ax1 += bflo(v1); ay1 += bfhi(v1);
            ax2 += bflo(v2); ay2 += bfhi(v2);
            ax3 += bflo(v3); ay3 += bfhi(v3);
        }
        for (; j < dmain; ++j) {
            int s0 = __shfl(nid, j);
            u32 v0 = *(const u32*)(xb + ((size_t)s0 << 7) + 2 * lane);
            ax0 += bflo(v0); ay0 += bfhi(v0);
        }
        for (int t = b0 + 64; t < b0 + deg; ++t) {   // rare deg>64 tail
            int s0 = ssrc[t];
            u32 v0 = *(const u32*)(xb + ((size_t)s0 << 7) + 2 * lane);
            ax0 += bflo(v0); ay0 += bfhi(v0);
        }
        float ax = (ax0 + ax1) + (ax2 + ax3);
        float ay = (ay0 + ay1) + (ay2 + ay3);
        u32 pk = (u32)f2bf(ax) | ((u32)f2bf(ay) << 16);
        int c = (2 * lane) ^ ((rr & 7) << 3);
        *(u32*)&hs[rr * 128 + c] = pk;
    }
    __syncthreads();

    const int m = lane & 15;
    const int ko = (lane >> 4) * 8;
    const int rb = (wave & 3) * 16;               // row block (16 rows)
    const int cbase = (wave >> 2) * (DOUT / 2);   // col half
    constexpr int NT = DOUT / 32;                 // 16-col tiles per wave

    // ---- GEMM1: ts = relu(hs @ w1 + b1) ----
    {
        const int rr = rb + m;
        const int sw = (rr & 7) << 3;
        bf16x8 a1[4];
#pragma unroll
        for (int s = 0; s < 4; ++s)
            a1[s] = *(const bf16x8*)&hs[rr * 128 + ((s * 32 + ko) ^ sw)];
        f32x4 acc[NT];
#pragma unroll
        for (int nt = 0; nt < NT; ++nt) acc[nt] = (f32x4){0.f, 0.f, 0.f, 0.f};
#pragma unroll
        for (int nt = 0; nt < NT; ++nt) {
            int n = cbase + nt * 16 + m;
#pragma unroll
            for (int s = 0; s < 4; ++s) {
                bf16x8 bf = *(const bf16x8*)&w1t[(size_t)n * 128 + s * 32 + ko];
                acc[nt] = __builtin_amdgcn_mfma_f32_16x16x32_bf16(a1[s], bf, acc[nt], 0, 0, 0);
            }
        }
#pragma unroll
        for (int nt = 0; nt < NT; ++nt) {
            int n = cbase + nt * 16 + m;
            float bias = b1[n];
#pragma unroll
            for (int j2 = 0; j2 < 4; ++j2) {
                int dr = rb + (lane >> 4) * 4 + j2;   // D: col=lane&15, row=(lane>>4)*4+reg
                float v = fmaxf(acc[nt][j2] + bias, 0.f);
                ts[dr * DOUT + (n ^ ((dr & 7) << 3))] = f2bf(v);
            }
        }
    }
    __syncthreads();   // after this barrier all hs reads are complete -> yb may overlay

    // ---- GEMM2: y = ts @ w2 + b2 ----
    {
        const int rr = rb + m;
        const int sw = (rr & 7) << 3;
        constexpr int KS = DOUT / 32;
        bf16x8 a2[KS];
#pragma unroll
        for (int s = 0; s < KS; ++s)
            a2[s] = *(const bf16x8*)&ts[rr * DOUT + ((s * 32 + ko) ^ sw)];
        f32x4 acc[NT];
#pragma unroll
        for (int nt = 0; nt < NT; ++nt) acc[nt] = (f32x4){0.f, 0.f, 0.f, 0.f};
#pragma unroll
        for (int nt = 0; nt < NT; ++nt) {
            int n = cbase + nt * 16 + m;
#pragma unroll
            for (int s = 0; s < KS; ++s) {
                bf16x8 bf = *(const bf16x8*)&w2t[(size_t)n * DOUT + s * 32 + ko];
                acc[nt] = __builtin_amdgcn_mfma_f32_16x16x32_bf16(a2[s], bf, acc[nt], 0, 0, 0);
            }
        }
        if (POOL) {
            // stage f32 y rows (+bias) into LDS, then segmented block reduce
#pragma unroll
            for (int nt = 0; nt < NT; ++nt) {
                int n = cbase + nt * 16 + m;
                float bias = b2[n];
#pragma unroll
                for (int j2 = 0; j2 < 4; ++j2) {
                    int dr = rb + (lane >> 4) * 4 + j2;
                    yb[dr * YB_ST + n] = acc[nt][j2] + bias;
                }
            }
            __syncthreads();
            // gid runs (batch sorted): ballot on boundaries, identical per wave
            int gl = gids[lane];
            int gp = (lane > 0) ? gids[lane - 1] : gl;
            unsigned long long mask = __ballot(lane > 0 && gl != gp) | 1ull;
            int nruns = (int)__popcll(mask);
            int c = tid >> 3, s = tid & 7;       // channel, slot (8 lanes/channel)
            unsigned long long mm = mask;
            for (int r = 0; r < nruns; ++r) {
                int start = (int)__builtin_ctzll(mm);
                mm &= mm - 1;
                int end = mm ? (int)__builtin_ctzll(mm) : 64;
                int gid = gids[start];
                if (gid >= 0) {
                    float sum = 0.f;
                    for (int n2 = start + s; n2 < end; n2 += 8)
                        sum += yb[n2 * YB_ST + c];
                    sum += __shfl_xor(sum, 1);
                    sum += __shfl_xor(sum, 2);
                    sum += __shfl_xor(sum, 4);
                    if (s == 0)
                        atomicAdd(&((float*)yout)[(size_t)gid * DOUT + c], sum);
                }
            }
        } else {
#pragma unroll
            for (int nt = 0; nt < NT; ++nt) {
                int n = cbase + nt * 16 + m;
                float bias = b2[n];
#pragma unroll
                for (int j2 = 0; j2 < 4; ++j2) {
                    int dr = rb + (lane >> 4) * 4 + j2;
                    int node = base + dr;
                    if (node < N_NODES) {
                        float v = acc[nt][j2] + bias;
                        if (RELU_OUT) v = fmaxf(v, 0.f);
                        ((u16*)yout)[(size_t)node * DOUT + n] = f2bf(v);
                    }
                }
            }
        }
    }
}

extern "C" void kernel_launch(void* const* d_in, const int* in_sizes, int n_in,
                              void* d_out, int out_size, void* d_ws, size_t ws_size,
                              hipStream_t stream) {
    const float* x     = (const float*)d_in[0];
    const int*   ei    = (const int*)d_in[1];
    const int*   batch = (const int*)d_in[2];
    const float* w1[3] = {(const float*)d_in[3], (const float*)d_in[7],  (const float*)d_in[11]};
    const float* b1[3] = {(const float*)d_in[4], (const float*)d_in[8],  (const float*)d_in[12]};
    const float* w2[3] = {(const float*)d_in[5], (const float*)d_in[9],  (const float*)d_in[13]};
    const float* b2[3] = {(const float*)d_in[6], (const float*)d_in[10], (const float*)d_in[14]};
    float* out = (float*)d_out;

    char* ws = (char*)d_ws;
    int*   cursor  = (int*)(ws + 0);          // 50000 ints (also histogram counts)
    int*   offsets = (int*)(ws + 200192);     // 50001 ints
    int*   bsum    = (int*)(ws + 400640);     // 196 ints
    int*   flag    = (int*)(ws + 401664);     // 1 int
    int*   ssrc    = (int*)(ws + 401920);     // 600000 ints
    u16*   xb      = (u16*)(ws + 2801920);    // 50000*128 bf16
    u16*   yA      = (u16*)(ws + 15601920);   // 50000*128 bf16
    u16*   yB      = (u16*)(ws + 28401920);   // 50000*128 bf16
    u16*   wts     = (u16*)(ws + 41201920);   // transposed bf16 weights
    u16* w1t0 = wts +      0;   // [128][128]
    u16* w2t0 = wts +  16384;   // [128][128]
    u16* w1t1 = wts +  32768;   // [128][128]
    u16* w2t1 = wts +  49152;   // [128][128]
    u16* w1t2 = wts +  65536;   // [64][128]
    u16* w2t2 = wts +  73728;   // [64][64]

    detect_kernel<<<1, 64, 0, stream>>>(ei, flag);

    (void)hipMemsetAsync(cursor, 0, N_NODES * sizeof(int), stream);
    hist_kernel<<<(N_EDGES + 255) / 256, 256, 0, stream>>>(ei, flag, cursor);
    scan1<<<196, 256, 0, stream>>>(cursor, offsets, bsum);
    scan2<<<1, 256, 0, stream>>>(bsum, 196);
    scan3<<<196, 256, 0, stream>>>(offsets, bsum, cursor);
    scatter_kernel<<<(N_EDGES + 255) / 256, 256, 0, stream>>>(ei, flag, cursor, ssrc);

    cvt_x<<<6250, 256, 0, stream>>>(x, xb);
    CvtAll ca;
    ca.d[0] = {w1[0], w1t0, 128, 128, 4,  0};
    ca.d[1] = {w2[0], w2t0, 128, 128, 4, 16};
    ca.d[2] = {w1[1], w1t1, 128, 128, 4, 32};
    ca.d[3] = {w2[1], w2t1, 128, 128, 4, 48};
    ca.d[4] = {w1[2], w1t2, 128,  64, 4, 64};
    ca.d[5] = {w2[2], w2t2,  64,  64, 2, 72};
    cvt_wt_all<<<76, 256, 0, stream>>>(ca);

    (void)hipMemsetAsync(out, 0, (size_t)out_size * sizeof(float), stream);

    const int NB = (N_NODES + 63) / 64;   // 782
    fused_layer<128, 1, 0><<<NB, 512, 0, stream>>>(xb, offsets, ssrc, w1t0, b1[0], w2t0, b2[0], batch, flag, yA);
    fused_layer<128, 1, 0><<<NB, 512, 0, stream>>>(yA, offsets, ssrc, w1t1, b1[1], w2t1, b2[1], batch, flag, yB);
    fused_layer< 64, 0, 1><<<NB, 512, 0, stream>>>(yB, offsets, ssrc, w1t2, b1[2], w2t2, b2[2], batch, flag, out);
}

// Round 7
// 224.547 us; speedup vs baseline: 1.2421x; 1.0463x over previous
//
#include <hip/hip_runtime.h>

#define N_NODES 50000
#define N_EDGES 600000
#define N_GRAPHS 512

typedef unsigned int u32;
typedef unsigned short u16;
typedef __attribute__((ext_vector_type(8))) short bf16x8;
typedef __attribute__((ext_vector_type(4))) float f32x4;

__device__ __forceinline__ float bflo(u32 v) { return __uint_as_float(v << 16); }
__device__ __forceinline__ float bfhi(u32 v) { return __uint_as_float(v & 0xffff0000u); }
__device__ __forceinline__ u16 f2bf(float f) {
    u32 x = __float_as_uint(f);
    return (u16)((x + 0x7fffu + ((x >> 16) & 1u)) >> 16);
}
__device__ __forceinline__ void addrow(float* a, uint4 v) {
    a[0] += bflo(v.x); a[1] += bfhi(v.x);
    a[2] += bflo(v.y); a[3] += bfhi(v.y);
    a[4] += bflo(v.z); a[5] += bfhi(v.z);
    a[6] += bflo(v.w); a[7] += bfhi(v.w);
}

__device__ __forceinline__ int idx_at(const int* __restrict__ a, int i, int wide) {
    return wide ? a[2 * i] : a[i];          // little-endian low word; values < 2^31
}

// ---------------- init: zero histogram + index-width detect ----------------
__global__ void init_kernel(const int* __restrict__ ei, int* __restrict__ cnt,
                            int* __restrict__ flag) {
    int i = blockIdx.x * 256 + threadIdx.x;
    if (i < N_NODES) cnt[i] = 0;
    if (blockIdx.x == 0 && threadIdx.x < 64) {
        int v = ei[2 * threadIdx.x + 1];    // odd words: int64 hi OR int32 src[2k+1]
        unsigned long long nz = __ballot(v != 0);
        if (threadIdx.x == 0) *flag = (nz == 0ull) ? 1 : 0;   // all zero -> int64
    }
}

// ---------------- CSR build ----------------
__global__ void hist_kernel(const int* __restrict__ ei, const int* __restrict__ flag,
                            int* __restrict__ cnt) {
    int e = blockIdx.x * 256 + threadIdx.x;
    if (e >= N_EDGES) return;
    int w = *flag;
    const int* dst = ei + (w ? 2 * N_EDGES : N_EDGES);
    atomicAdd(&cnt[idx_at(dst, e, w)], 1);
}

__global__ void scan1(const int* __restrict__ cnt, int* __restrict__ excl,
                      int* __restrict__ bsum) {
    __shared__ int s[256];
    int tid = threadIdx.x;
    int i = blockIdx.x * 256 + tid;
    int v = (i < N_NODES) ? cnt[i] : 0;
    s[tid] = v; __syncthreads();
    for (int off = 1; off < 256; off <<= 1) {
        int t = (tid >= off) ? s[tid - off] : 0;
        __syncthreads();
        s[tid] += t;
        __syncthreads();
    }
    if (i < N_NODES) excl[i] = s[tid] - v;
    if (tid == 255) bsum[blockIdx.x] = s[255];
}

__global__ void scan2(int* __restrict__ bsum, int nb) {
    __shared__ int s[256];
    int tid = threadIdx.x;
    int v = (tid < nb) ? bsum[tid] : 0;
    s[tid] = v; __syncthreads();
    for (int off = 1; off < 256; off <<= 1) {
        int t = (tid >= off) ? s[tid - off] : 0;
        __syncthreads();
        s[tid] += t;
        __syncthreads();
    }
    if (tid < nb) bsum[tid] = s[tid] - v;
}

__global__ void scan3(int* __restrict__ offsets, const int* __restrict__ bsum,
                      int* __restrict__ cursor) {
    int i = blockIdx.x * 256 + threadIdx.x;
    if (i < N_NODES) {
        int off = offsets[i] + bsum[i >> 8];
        offsets[i] = off;
        cursor[i] = off;
    }
    if (i == 0) offsets[N_NODES] = N_EDGES;
}

__global__ void scatter_kernel(const int* __restrict__ ei, const int* __restrict__ flag,
                               int* __restrict__ cursor, int* __restrict__ ssrc) {
    int e = blockIdx.x * 256 + threadIdx.x;
    if (e >= N_EDGES) return;
    int w = *flag;
    const int* src = ei;
    const int* dst = ei + (w ? 2 * N_EDGES : N_EDGES);
    int d = idx_at(dst, e, w);
    int pos = atomicAdd(&cursor[d], 1);
    ssrc[pos] = idx_at(src, e, w);
}

// ---------------- converts (cvt_x also zeroes d_out for the fused pool) ------
__global__ void cvt_x(const float* __restrict__ in, u16* __restrict__ out,
                      float* __restrict__ outz) {
    size_t i = (size_t)blockIdx.x * 256 + threadIdx.x;   // 1.6M threads, 4 elems each
    if (blockIdx.x < 32) {                               // zero 512*64 f32 output
        int t = blockIdx.x * 256 + threadIdx.x;
        float4 z = {0.f, 0.f, 0.f, 0.f};
        *(float4*)&outz[t * 4] = z;
    }
    float4 v = *(const float4*)&in[i * 4];
    u32 o0 = (u32)f2bf(v.x) | ((u32)f2bf(v.y) << 16);
    u32 o1 = (u32)f2bf(v.z) | ((u32)f2bf(v.w) << 16);
    uint2 o; o.x = o0; o.y = o1;
    *(uint2*)&out[i * 4] = o;
}

// all 6 weight transposes in one launch: w [K][N] f32 -> wt [N][K] bf16
struct CvtDesc { const float* w; u16* wt; int K, N, bx, bstart; };
struct CvtAll { CvtDesc d[6]; };
__global__ void cvt_wt_all(CvtAll all) {
    __shared__ float tile[32][33];
    int b = blockIdx.x;
    int di = 0;
#pragma unroll
    for (int i = 1; i < 6; ++i) if (b >= all.d[i].bstart) di = i;
    CvtDesc d = all.d[di];
    int rel = b - d.bstart;
    int bk = (rel % d.bx) * 32, bn = (rel / d.bx) * 32;
    int tx = threadIdx.x & 31, ty = threadIdx.x >> 5;   // 32 x 8
#pragma unroll
    for (int yy = 0; yy < 32; yy += 8)
        tile[ty + yy][tx] = d.w[(size_t)(bk + ty + yy) * d.N + bn + tx];
    __syncthreads();
#pragma unroll
    for (int yy = 0; yy < 32; yy += 8)
        d.wt[(size_t)(bn + ty + yy) * d.K + bk + tx] = f2bf(tile[tx][ty + yy]);
}

// ---------------- fused GIN layer: agg -> GEMM1(+b,ReLU) -> GEMM2(+b,[ReLU]) ----
// xb: bf16 [N_NODES][128]; w1t: bf16 [DOUT][128]; w2t: bf16 [DOUT][DOUT]
// Gather: each 16-lane group owns ONE node (4 nodes/wave concurrent, uint4 rows,
// no cross-lane ops inside divergent regions).
// POOL: segment-reduce y rows in-block (batch sorted), few atomics into yout f32
template <int DOUT, int RELU_OUT, int POOL>
__global__ __launch_bounds__(512) void fused_layer(
    const u16* __restrict__ xb, const int* __restrict__ offsets,
    const int* __restrict__ ssrc,
    const u16* __restrict__ w1t, const float* __restrict__ b1,
    const u16* __restrict__ w2t, const float* __restrict__ b2,
    const int* __restrict__ batch, const int* __restrict__ flagp,
    void* __restrict__ yout)
{
    constexpr int YB_ST = 66;                          // f32 stride (bank-spread)
    constexpr int HSB = 64 * 128 * 2;                  // 16384 B
    constexpr int AB = POOL ? (64 * YB_ST * 4) : HSB;  // ybuf overlays dead hs
    constexpr int ABM = AB > HSB ? AB : HSB;
    __shared__ __attribute__((aligned(16))) char smemA[ABM];
    __shared__ __attribute__((aligned(16))) u16 ts[64 * DOUT];
    __shared__ int gids[64];
    u16* hs = (u16*)smemA;          // h tile, XOR-swizzled rows
    float* yb = (float*)smemA;      // POOL: f32 y stage (valid after hs is dead)

    const int tid = threadIdx.x;
    const int wave = tid >> 6, lane = tid & 63;
    const int g = lane >> 4;        // 4 groups of 16 lanes; group owns a node
    const int l = lane & 15;
    const int base = blockIdx.x * 64;
    const int wflag = POOL ? *flagp : 0;

    if (POOL && tid < 64) {
        int node = base + tid;
        gids[tid] = (node < N_NODES) ? idx_at(batch, node, wflag) : -1;
    }

    // ---- phase A: gather-aggregate; 4 nodes per wave, 16B/lane, 4-deep ----
    for (int it = 0; it < 2; ++it) {
        int rr = wave * 8 + it * 4 + g;
        int node = base + rr;
        if (node < N_NODES) {                 // group-divergent: no wave ops inside
            uint4 sv = *(const uint4*)(xb + ((size_t)node << 7) + l * 8);
            float acc[8] = { bflo(sv.x), bfhi(sv.x), bflo(sv.y), bfhi(sv.y),
                             bflo(sv.z), bfhi(sv.z), bflo(sv.w), bfhi(sv.w) };
            int b0 = offsets[node];
            int deg = offsets[node + 1] - b0;
            const int* sp = ssrc + b0;
            int j = 0;
            for (; j + 4 <= deg; j += 4) {    // 16 rows in flight per wave
                int s0 = sp[j], s1 = sp[j + 1], s2 = sp[j + 2], s3 = sp[j + 3];
                uint4 v0 = *(const uint4*)(xb + ((size_t)s0 << 7) + l * 8);
                uint4 v1 = *(const uint4*)(xb + ((size_t)s1 << 7) + l * 8);
                uint4 v2 = *(const uint4*)(xb + ((size_t)s2 << 7) + l * 8);
                uint4 v3 = *(const uint4*)(xb + ((size_t)s3 << 7) + l * 8);
                addrow(acc, v0); addrow(acc, v1);
                addrow(acc, v2); addrow(acc, v3);
            }
            for (; j < deg; ++j) {
                int s0 = sp[j];
                uint4 v0 = *(const uint4*)(xb + ((size_t)s0 << 7) + l * 8);
                addrow(acc, v0);
            }
            uint4 o;
            o.x = (u32)f2bf(acc[0]) | ((u32)f2bf(acc[1]) << 16);
            o.y = (u32)f2bf(acc[2]) | ((u32)f2bf(acc[3]) << 16);
            o.z = (u32)f2bf(acc[4]) | ((u32)f2bf(acc[5]) << 16);
            o.w = (u32)f2bf(acc[6]) | ((u32)f2bf(acc[7]) << 16);
            int c = (l * 8) ^ ((rr & 7) << 3);
            *(uint4*)&hs[rr * 128 + c] = o;
        }
    }
    __syncthreads();

    const int m = lane & 15;
    const int ko = (lane >> 4) * 8;
    const int rb = (wave & 3) * 16;               // row block (16 rows)
    const int cbase = (wave >> 2) * (DOUT / 2);   // col half
    constexpr int NT = DOUT / 32;                 // 16-col tiles per wave

    // ---- GEMM1: ts = relu(hs @ w1 + b1) ----
    {
        const int rr = rb + m;
        const int sw = (rr & 7) << 3;
        bf16x8 a1[4];
#pragma unroll
        for (int s = 0; s < 4; ++s)
            a1[s] = *(const bf16x8*)&hs[rr * 128 + ((s * 32 + ko) ^ sw)];
        f32x4 acc[NT];
#pragma unroll
        for (int nt = 0; nt < NT; ++nt) acc[nt] = (f32x4){0.f, 0.f, 0.f, 0.f};
#pragma unroll
        for (int nt = 0; nt < NT; ++nt) {
            int n = cbase + nt * 16 + m;
#pragma unroll
            for (int s = 0; s < 4; ++s) {
                bf16x8 bf = *(const bf16x8*)&w1t[(size_t)n * 128 + s * 32 + ko];
                acc[nt] = __builtin_amdgcn_mfma_f32_16x16x32_bf16(a1[s], bf, acc[nt], 0, 0, 0);
            }
        }
#pragma unroll
        for (int nt = 0; nt < NT; ++nt) {
            int n = cbase + nt * 16 + m;
            float bias = b1[n];
#pragma unroll
            for (int j2 = 0; j2 < 4; ++j2) {
                int dr = rb + (lane >> 4) * 4 + j2;   // D: col=lane&15, row=(lane>>4)*4+reg
                float v = fmaxf(acc[nt][j2] + bias, 0.f);
                ts[dr * DOUT + (n ^ ((dr & 7) << 3))] = f2bf(v);
            }
        }
    }
    __syncthreads();   // after this barrier all hs reads are complete -> yb may overlay

    // ---- GEMM2: y = ts @ w2 + b2 ----
    {
        const int rr = rb + m;
        const int sw = (rr & 7) << 3;
        constexpr int KS = DOUT / 32;
        bf16x8 a2[KS];
#pragma unroll
        for (int s = 0; s < KS; ++s)
            a2[s] = *(const bf16x8*)&ts[rr * DOUT + ((s * 32 + ko) ^ sw)];
        f32x4 acc[NT];
#pragma unroll
        for (int nt = 0; nt < NT; ++nt) acc[nt] = (f32x4){0.f, 0.f, 0.f, 0.f};
#pragma unroll
        for (int nt = 0; nt < NT; ++nt) {
            int n = cbase + nt * 16 + m;
#pragma unroll
            for (int s = 0; s < KS; ++s) {
                bf16x8 bf = *(const bf16x8*)&w2t[(size_t)n * DOUT + s * 32 + ko];
                acc[nt] = __builtin_amdgcn_mfma_f32_16x16x32_bf16(a2[s], bf, acc[nt], 0, 0, 0);
            }
        }
        if (POOL) {
            // stage f32 y rows (+bias) into LDS, then segmented block reduce
#pragma unroll
            for (int nt = 0; nt < NT; ++nt) {
                int n = cbase + nt * 16 + m;
                float bias = b2[n];
#pragma unroll
                for (int j2 = 0; j2 < 4; ++j2) {
                    int dr = rb + (lane >> 4) * 4 + j2;
                    yb[dr * YB_ST + n] = acc[nt][j2] + bias;
                }
            }
            __syncthreads();
            // gid runs (batch sorted): ballot on boundaries, identical per wave
            int gl = gids[lane];
            int gp = (lane > 0) ? gids[lane - 1] : gl;
            unsigned long long mask = __ballot(lane > 0 && gl != gp) | 1ull;
            int nruns = (int)__popcll(mask);
            int c = tid >> 3, s = tid & 7;       // channel, slot (8 lanes/channel)
            unsigned long long mm = mask;
            for (int r = 0; r < nruns; ++r) {
                int start = (int)__builtin_ctzll(mm);
                mm &= mm - 1;
                int end = mm ? (int)__builtin_ctzll(mm) : 64;
                int gid = gids[start];
                if (gid >= 0) {
                    float sum = 0.f;
                    for (int n2 = start + s; n2 < end; n2 += 8)
                        sum += yb[n2 * YB_ST + c];
                    sum += __shfl_xor(sum, 1);
                    sum += __shfl_xor(sum, 2);
                    sum += __shfl_xor(sum, 4);
                    if (s == 0)
                        atomicAdd(&((float*)yout)[(size_t)gid * DOUT + c], sum);
                }
            }
        } else {
#pragma unroll
            for (int nt = 0; nt < NT; ++nt) {
                int n = cbase + nt * 16 + m;
                float bias = b2[n];
#pragma unroll
                for (int j2 = 0; j2 < 4; ++j2) {
                    int dr = rb + (lane >> 4) * 4 + j2;
                    int node = base + dr;
                    if (node < N_NODES) {
                        float v = acc[nt][j2] + bias;
                        if (RELU_OUT) v = fmaxf(v, 0.f);
                        ((u16*)yout)[(size_t)node * DOUT + n] = f2bf(v);
                    }
                }
            }
        }
    }
}

extern "C" void kernel_launch(void* const* d_in, const int* in_sizes, int n_in,
                              void* d_out, int out_size, void* d_ws, size_t ws_size,
                              hipStream_t stream) {
    const float* x     = (const float*)d_in[0];
    const int*   ei    = (const int*)d_in[1];
    const int*   batch = (const int*)d_in[2];
    const float* w1[3] = {(const float*)d_in[3], (const float*)d_in[7],  (const float*)d_in[11]};
    const float* b1[3] = {(const float*)d_in[4], (const float*)d_in[8],  (const float*)d_in[12]};
    const float* w2[3] = {(const float*)d_in[5], (const float*)d_in[9],  (const float*)d_in[13]};
    const float* b2[3] = {(const float*)d_in[6], (const float*)d_in[10], (const float*)d_in[14]};
    float* out = (float*)d_out;

    char* ws = (char*)d_ws;
    int*   cursor  = (int*)(ws + 0);          // 50000 ints (also histogram counts)
    int*   offsets = (int*)(ws + 200192);     // 50001 ints
    int*   bsum    = (int*)(ws + 400640);     // 196 ints
    int*   flag    = (int*)(ws + 401664);     // 1 int
    int*   ssrc    = (int*)(ws + 401920);     // 600000 ints
    u16*   xb      = (u16*)(ws + 2801920);    // 50000*128 bf16
    u16*   yA      = (u16*)(ws + 15601920);   // 50000*128 bf16
    u16*   yB      = (u16*)(ws + 28401920);   // 50000*128 bf16
    u16*   wts     = (u16*)(ws + 41201920);   // transposed bf16 weights
    u16* w1t0 = wts +      0;   // [128][128]
    u16* w2t0 = wts +  16384;   // [128][128]
    u16* w1t1 = wts +  32768;   // [128][128]
    u16* w2t1 = wts +  49152;   // [128][128]
    u16* w1t2 = wts +  65536;   // [64][128]
    u16* w2t2 = wts +  73728;   // [64][64]

    init_kernel<<<196, 256, 0, stream>>>(ei, cursor, flag);
    hist_kernel<<<(N_EDGES + 255) / 256, 256, 0, stream>>>(ei, flag, cursor);
    scan1<<<196, 256, 0, stream>>>(cursor, offsets, bsum);
    scan2<<<1, 256, 0, stream>>>(bsum, 196);
    scan3<<<196, 256, 0, stream>>>(offsets, bsum, cursor);
    scatter_kernel<<<(N_EDGES + 255) / 256, 256, 0, stream>>>(ei, flag, cursor, ssrc);

    cvt_x<<<6250, 256, 0, stream>>>(x, xb, out);
    CvtAll ca;
    ca.d[0] = {w1[0], w1t0, 128, 128, 4,  0};
    ca.d[1] = {w2[0], w2t0, 128, 128, 4, 16};
    ca.d[2] = {w1[1], w1t1, 128, 128, 4, 32};
    ca.d[3] = {w2[1], w2t1, 128, 128, 4, 48};
    ca.d[4] = {w1[2], w1t2, 128,  64, 4, 64};
    ca.d[5] = {w2[2], w2t2,  64,  64, 2, 72};
    cvt_wt_all<<<76, 256, 0, stream>>>(ca);

    const int NB = (N_NODES + 63) / 64;   // 782
    fused_layer<128, 1, 0><<<NB, 512, 0, stream>>>(xb, offsets, ssrc, w1t0, b1[0], w2t0, b2[0], batch, flag, yA);
    fused_layer<128, 1, 0><<<NB, 512, 0, stream>>>(yA, offsets, ssrc, w1t1, b1[1], w2t1, b2[1], batch, flag, yB);
    fused_layer< 64, 0, 1><<<NB, 512, 0, stream>>>(yB, offsets, ssrc, w1t2, b1[2], w2t2, b2[2], batch, flag, out);
}